// Round 1
// baseline (37.228 us; speedup 1.0000x reference)
//
#include <hip/hip_runtime.h>

#define NN 512
#define TS 32

// C[i,j] = sum_{k=i}^{j} A[i,k]*B[k,j], A/B packed row-major upper-triangular.
// packed index of (i,k), k>=i:  i*(2N-i+1)/2 + (k-i)
__global__ __launch_bounds__(256) void ut_mm(const float* __restrict__ A,
                                             const float* __restrict__ B,
                                             float* __restrict__ C) {
    const int bj = blockIdx.x;   // column tile
    const int bi = blockIdx.y;   // row tile
    const int tid = (int)threadIdx.x;
    const int tx = tid & 31;     // column within tile
    const int ty = tid >> 5;     // 0..7, row group
    const int r0 = bi * TS;
    const int c0 = bj * TS;

    if (bj < bi) {
        // strictly below the diagonal: structurally zero
        #pragma unroll
        for (int s = 0; s < 4; ++s) {
            C[(r0 + ty + s * 8) * NN + c0 + tx] = 0.0f;
        }
        return;
    }

    __shared__ float As[TS][TS];
    __shared__ float Bs[TS][TS];

    float acc[4] = {0.f, 0.f, 0.f, 0.f};

    // k only needs to span [r0, c0+TS): A[i,k]=0 for k<i>=r0, B[k,j]=0 for k>j<c0+TS
    for (int k0 = r0; k0 < c0 + TS; k0 += TS) {
        // stage A tile: rows i in [r0, r0+32), cols k in [k0, k0+32)
        #pragma unroll
        for (int s = 0; s < 4; ++s) {
            const int i = r0 + ty + s * 8;
            const int k = k0 + tx;
            float v = 0.0f;
            if (k >= i) {
                const int pidx = (i * (2 * NN - i + 1)) / 2 + (k - i);
                v = A[pidx];
            }
            As[ty + s * 8][tx] = v;
        }
        // stage B tile: rows k in [k0, k0+32), cols j in [c0, c0+32)
        #pragma unroll
        for (int s = 0; s < 4; ++s) {
            const int k = k0 + ty + s * 8;
            const int j = c0 + tx;
            float v = 0.0f;
            if (j >= k) {
                const int pidx = (k * (2 * NN - k + 1)) / 2 + (j - k);
                v = B[pidx];
            }
            Bs[ty + s * 8][tx] = v;
        }
        __syncthreads();

        #pragma unroll
        for (int kk = 0; kk < TS; ++kk) {
            const float b = Bs[kk][tx];
            acc[0] += As[ty][kk] * b;
            acc[1] += As[ty + 8][kk] * b;
            acc[2] += As[ty + 16][kk] * b;
            acc[3] += As[ty + 24][kk] * b;
        }
        __syncthreads();
    }

    #pragma unroll
    for (int s = 0; s < 4; ++s) {
        C[(r0 + ty + s * 8) * NN + c0 + tx] = acc[s];
    }
}

extern "C" void kernel_launch(void* const* d_in, const int* in_sizes, int n_in,
                              void* d_out, int out_size, void* d_ws, size_t ws_size,
                              hipStream_t stream) {
    const float* A = (const float*)d_in[0];
    const float* B = (const float*)d_in[1];
    float* C = (float*)d_out;
    dim3 grid(NN / TS, NN / TS);  // (16, 16): x = column tile, y = row tile
    ut_mm<<<grid, dim3(256), 0, stream>>>(A, B, C);
}

// Round 2
// 30.571 us; speedup vs baseline: 1.2177x; 1.2177x over previous
//
#include <hip/hip_runtime.h>

#define NN 512

// C[i,j] = sum_{k=i}^{j} A[i,k]*B[k,j]; A,B packed row-major upper-triangular.
// packed index of (r, c), c >= r:  r*(2N - r + 1)/2 + (c - r)
//
// One wave = one row i, 64 consecutive columns j = base..base+63.
//  - A[i,k]: wave-uniform address (broadcast, L1-resident row ~2KB)
//  - B[k,j]: lanes read consecutive packed addresses (coalesced)
//  - idxB(k+1) - idxB(k) = N-1-k  -> one add per iteration
__global__ __launch_bounds__(256) void ut_rowwave(const float* __restrict__ A,
                                                  const float* __restrict__ B,
                                                  float* __restrict__ C) {
    const int g = blockIdx.x * 256 + (int)threadIdx.x;  // 0 .. N*N-1
    const int i = g >> 9;            // row (uniform per wave: 512 % 64 == 0)
    const int j = g & (NN - 1);      // column
    const int lane = (int)threadIdx.x & 63;
    const int base = j - lane;       // wave's first column (uniform)

    if (i > base + 63) {             // whole wave strictly below diagonal
        C[g] = 0.0f;
        return;
    }

    const int rowA = (i * (2 * NN - i + 1)) >> 1;  // packed offset of (i, i)

    int k = i;
    int idxA = rowA;                                      // element (i, k)
    int idxB = ((k * (2 * NN - k + 1)) >> 1) + (j - k);   // element (k, j)

    float a0 = 0.f, a1 = 0.f, a2 = 0.f, a3 = 0.f;

    // ---- phase 1: k in [i, base) — every lane has j >= base > k, no mask ----
    const int p1end = base;
    for (; k + 4 <= p1end; k += 4) {
        const float b0 = B[idxB];
        const int ib1 = idxB + (NN - 1 - k);
        const float b1 = B[ib1];
        const int ib2 = ib1 + (NN - 2 - k);
        const float b2 = B[ib2];
        const int ib3 = ib2 + (NN - 3 - k);
        const float b3 = B[ib3];
        idxB = ib3 + (NN - 4 - k);
        a0 += A[idxA]     * b0;
        a1 += A[idxA + 1] * b1;
        a2 += A[idxA + 2] * b2;
        a3 += A[idxA + 3] * b3;
        idxA += 4;
    }
    for (; k < p1end; ++k) {
        a0 += A[idxA] * B[idxB];
        ++idxA;
        idxB += (NN - 1 - k);
    }

    float acc = (a0 + a1) + (a2 + a3);

    // ---- phase 2: k in [max(i,base), min(base+63, N-1)], masked by k <= j ----
    const int p2end = (base + 63 < NN - 1) ? (base + 63) : (NN - 1);
    for (; k <= p2end; ++k) {
        const float bv = B[idxB];          // index stays in-bounds even if j < k
        acc += A[idxA] * ((k <= j) ? bv : 0.0f);
        ++idxA;
        idxB += (NN - 1 - k);
    }

    C[g] = (j >= i) ? acc : 0.0f;
}

extern "C" void kernel_launch(void* const* d_in, const int* in_sizes, int n_in,
                              void* d_out, int out_size, void* d_ws, size_t ws_size,
                              hipStream_t stream) {
    const float* A = (const float*)d_in[0];
    const float* B = (const float*)d_in[1];
    float* C = (float*)d_out;
    ut_rowwave<<<dim3(NN * NN / 256), dim3(256), 0, stream>>>(A, B, C);
}

// Round 4
// 30.479 us; speedup vs baseline: 1.2214x; 1.0030x over previous
//
#include <hip/hip_runtime.h>

#define NN 512
#define PELEMS (NN * NN)  // 262144 = 1<<18

// ---------------- stage 1: split-K partial sums ----------------
// One wave = (row pair i0,i0+1) x (64-col tile jtile) x (64-k chunk kc).
// Writes P[kc][i][j] for its two rows. Only triples with
// itile <= kc <= jtile are valid; stage 2 reads exactly those.
__global__ __launch_bounds__(256) void ut_partial(const float* __restrict__ A,
                                                  const float* __restrict__ B,
                                                  float* __restrict__ P) {
    const int wid = ((int)blockIdx.x << 2) + ((int)threadIdx.x >> 6);
    const int lane = (int)threadIdx.x & 63;
    const int kc = wid & 7;
    const int t = wid >> 3;
    const int jtile = t & 7;
    const int rp = t >> 3;  // 0..255
    const int i0 = rp << 1;
    const int i1 = i0 + 1;
    const int itile = i0 >> 6;
    if (jtile < itile || kc < itile || kc > jtile) return;

    const int j = (jtile << 6) + lane;
    const int kc64 = kc << 6;

    const int rowA0 = (i0 * (2 * NN - i0 + 1)) >> 1;
    const int rowA1 = (i1 * (2 * NN - i1 + 1)) >> 1;
    // pA[k] == element A(i, k); valid for k >= i (masked otherwise)
    const float* pA0 = A + (rowA0 - i0);
    const float* pA1 = A + (rowA1 - i1);

    int idxB = ((kc64 * (2 * NN - kc64 + 1)) >> 1) + (j - kc64);  // B(kc64, j)

    float acc0 = 0.f, acc1 = 0.f;

    if (kc > itile && kc < jtile) {
        // interior chunk: all 64 k's valid for both rows and all lanes
        #pragma unroll 8
        for (int k = kc64; k < kc64 + 64; ++k) {
            const float bv = B[idxB];
            acc0 += pA0[k] * bv;
            acc1 += pA1[k] * bv;
            idxB += NN - 1 - k;
        }
    } else {
        // boundary chunk: mask k >= i_r (row start) and k <= j (col end).
        // Masked loads execute only under exec-mask -> no OOB access.
        #pragma unroll 4
        for (int k = kc64; k < kc64 + 64; ++k) {
            const float bv = (k <= j) ? B[idxB] : 0.f;
            const float a0 = (k >= i0) ? pA0[k] : 0.f;
            const float a1 = (k >= i1) ? pA1[k] : 0.f;
            acc0 += a0 * bv;
            acc1 += a1 * bv;
            idxB += NN - 1 - k;
        }
    }

    P[(kc << 18) + (i0 << 9) + j] = acc0;
    P[(kc << 18) + (i1 << 9) + j] = acc1;
}

// ---------------- stage 2: deterministic chunk reduce ----------------
__global__ __launch_bounds__(256) void ut_reduce(const float* __restrict__ P,
                                                 float* __restrict__ C) {
    const int g = (int)blockIdx.x * 256 + (int)threadIdx.x;
    const int i = g >> 9;
    const int j = g & (NN - 1);
    float s = 0.f;
    if (j >= i) {
        const int k0 = i >> 6;
        const int k1 = j >> 6;  // uniform per wave (64-aligned j range)
        for (int kc = k0; kc <= k1; ++kc) s += P[(kc << 18) + g];
    }
    C[g] = s;
}

// ---------------- fallback (round-2 kernel) if d_ws too small ----------------
__global__ __launch_bounds__(256) void ut_rowwave(const float* __restrict__ A,
                                                  const float* __restrict__ B,
                                                  float* __restrict__ C) {
    const int g = (int)blockIdx.x * 256 + (int)threadIdx.x;
    const int i = g >> 9;
    const int j = g & (NN - 1);
    const int lane = (int)threadIdx.x & 63;
    const int base = j - lane;
    if (i > base + 63) { C[g] = 0.0f; return; }
    const int rowA = (i * (2 * NN - i + 1)) >> 1;
    int k = i;
    int idxA = rowA;
    int idxB = ((k * (2 * NN - k + 1)) >> 1) + (j - k);
    float a0 = 0.f, a1 = 0.f, a2 = 0.f, a3 = 0.f;
    const int p1end = base;
    for (; k + 4 <= p1end; k += 4) {
        const float b0 = B[idxB];
        const int ib1 = idxB + (NN - 1 - k);
        const float b1 = B[ib1];
        const int ib2 = ib1 + (NN - 2 - k);
        const float b2 = B[ib2];
        const int ib3 = ib2 + (NN - 3 - k);
        const float b3 = B[ib3];
        idxB = ib3 + (NN - 4 - k);
        a0 += A[idxA] * b0;
        a1 += A[idxA + 1] * b1;
        a2 += A[idxA + 2] * b2;
        a3 += A[idxA + 3] * b3;
        idxA += 4;
    }
    for (; k < p1end; ++k) {
        a0 += A[idxA] * B[idxB];
        ++idxA;
        idxB += (NN - 1 - k);
    }
    float acc = (a0 + a1) + (a2 + a3);
    const int p2end = (base + 63 < NN - 1) ? (base + 63) : (NN - 1);
    for (; k <= p2end; ++k) {
        const float bv = B[idxB];
        acc += A[idxA] * ((k <= j) ? bv : 0.0f);
        ++idxA;
        idxB += (NN - 1 - k);
    }
    C[g] = (j >= i) ? acc : 0.0f;
}

extern "C" void kernel_launch(void* const* d_in, const int* in_sizes, int n_in,
                              void* d_out, int out_size, void* d_ws, size_t ws_size,
                              hipStream_t stream) {
    const float* A = (const float*)d_in[0];
    const float* B = (const float*)d_in[1];
    float* C = (float*)d_out;

    const size_t needed = (size_t)PELEMS * 8 * sizeof(float);  // 8 MB
    if (ws_size >= needed) {
        float* P = (float*)d_ws;
        // stage 1: 256 row-pairs x 8 jtiles x 8 kchunks = 16384 waves = 4096 blocks
        ut_partial<<<dim3(4096), dim3(256), 0, stream>>>(A, B, P);
        // stage 2: one thread per output element
        ut_reduce<<<dim3(PELEMS / 256), dim3(256), 0, stream>>>(P, C);
    } else {
        ut_rowwave<<<dim3(PELEMS / 256), dim3(256), 0, stream>>>(A, B, C);
    }
}

// Round 7
// 22.085 us; speedup vs baseline: 1.6857x; 1.3801x over previous
//
#include <hip/hip_runtime.h>

#define NN 512
#define PELEMS (NN * NN)  // 262144 = 1<<18

// ---------------- stage 1: split-K partial sums (compact grid) ----------------
// One wave = (row pair i0,i0+1) x (64-col tile jtile) x (64-k chunk kc),
// launched ONLY for valid triples: itile <= kc <= jtile (3840 waves total).
// Writes P[kc][i][j]; stage 2 reads exactly the chunk range [i>>6, j>>6].
__global__ __launch_bounds__(256) void ut_partial(const float* __restrict__ A,
                                                  const float* __restrict__ B,
                                                  float* __restrict__ P) {
    const int wid = ((int)blockIdx.x << 2) + ((int)threadIdx.x >> 6);  // 0..3839
    const int lane = (int)threadIdx.x & 63;

    // --- compact decode: wid -> (rp, jtile, kc) over valid triples only ---
    // itile 'it' owns 32 row-pairs, each with T(8-it) (jtile,kc) pairs.
    const int woff[8]   = {0, 1152, 2048, 2720, 3200, 3520, 3712, 3808};
    const int npairs[8] = {36, 28, 21, 15, 10, 6, 3, 1};
    int it = 0;
    #pragma unroll
    for (int t = 1; t < 8; ++t) it += (wid >= woff[t]);
    const int local = wid - woff[it];
    const int np    = npairs[it];
    const int rpl   = (int)((unsigned)local / (unsigned)np);
    const int p     = local - rpl * np;
    // pair p -> (d = jtile-it, kc-it): triangular decode, T(d)=d(d+1)/2
    int d = 0;
    #pragma unroll
    for (int t = 1; t < 8; ++t) d += (p >= ((t * (t + 1)) >> 1));
    const int jtile = it + d;
    const int kc    = it + (p - ((d * (d + 1)) >> 1));
    const int rp    = (it << 5) + rpl;

    const int i0 = rp << 1;
    const int i1 = i0 + 1;
    const int j  = (jtile << 6) + lane;
    const int kc64 = kc << 6;

    const int rowA0 = (i0 * (2 * NN - i0 + 1)) >> 1;
    const int rowA1 = (i1 * (2 * NN - i1 + 1)) >> 1;
    // pA[k] == element A(i, k); valid for k >= i (masked otherwise)
    const float* pA0 = A + (rowA0 - i0);
    const float* pA1 = A + (rowA1 - i1);

    int idxB = ((kc64 * (2 * NN - kc64 + 1)) >> 1) + (j - kc64);  // B(kc64, j)

    float acc0 = 0.f, acc1 = 0.f;

    if (kc > it && kc < jtile) {
        // interior chunk: all 64 k's valid for both rows and all lanes
        #pragma unroll 16
        for (int k = kc64; k < kc64 + 64; ++k) {
            const float bv = B[idxB];
            acc0 += pA0[k] * bv;
            acc1 += pA1[k] * bv;
            idxB += NN - 1 - k;
        }
    } else {
        // boundary chunk: mask k >= i_r (row start) and k <= j (col end).
        // All idxB values stay within [0, PACKED_LEN) even when masked out.
        #pragma unroll 8
        for (int k = kc64; k < kc64 + 64; ++k) {
            const float bv = (k <= j) ? B[idxB] : 0.f;
            const float a0 = (k >= i0) ? pA0[k] : 0.f;
            const float a1 = (k >= i1) ? pA1[k] : 0.f;
            acc0 += a0 * bv;
            acc1 += a1 * bv;
            idxB += NN - 1 - k;
        }
    }

    P[(kc << 18) + (i0 << 9) + j] = acc0;
    P[(kc << 18) + (i1 << 9) + j] = acc1;
}

// ---------------- stage 2: deterministic chunk reduce ----------------
__global__ __launch_bounds__(256) void ut_reduce(const float* __restrict__ P,
                                                 float* __restrict__ C) {
    const int t0 = (int)blockIdx.x * 256 + (int)threadIdx.x;  // 0..65535
    #pragma unroll
    for (int s = 0; s < 4; ++s) {
        const int g = t0 + (s << 16);
        const int i = g >> 9;
        const int j = g & (NN - 1);
        float sum = 0.f;
        if (j >= i) {
            const int k0 = i >> 6;
            const int k1 = j >> 6;  // uniform per wave (64-aligned j range)
            for (int kc = k0; kc <= k1; ++kc) sum += P[(kc << 18) + g];
        }
        C[g] = sum;
    }
}

extern "C" void kernel_launch(void* const* d_in, const int* in_sizes, int n_in,
                              void* d_out, int out_size, void* d_ws, size_t ws_size,
                              hipStream_t stream) {
    const float* A = (const float*)d_in[0];
    const float* B = (const float*)d_in[1];
    float* C = (float*)d_out;
    float* P = (float*)d_ws;  // needs 8 MB; observed ws_size = 256 MiB

    // stage 1: 3840 valid waves = 960 blocks x 4 waves
    ut_partial<<<dim3(960), dim3(256), 0, stream>>>(A, B, P);
    // stage 2: 256 blocks x 256 threads x 4 elements
    ut_reduce<<<dim3(256), dim3(256), 0, stream>>>(P, C);
}